// Round 24
// baseline (212.593 us; speedup 1.0000x reference)
//
#include <hip/hip_runtime.h>
#include <math.h>

#define TWO_PI 6.283185307179586f

typedef __attribute__((ext_vector_type(8))) short bf16x8;
typedef __attribute__((ext_vector_type(4))) short bf16x4;
typedef __attribute__((ext_vector_type(4))) float f32x4;
typedef __attribute__((ext_vector_type(4))) _Float16 h16x4;
typedef __attribute__((ext_vector_type(8))) _Float16 h16x8;

__device__ __forceinline__ short f2bf(float f) {
    unsigned u = __float_as_uint(f);
    unsigned r = (u + 0x7FFFu + ((u >> 16) & 1u)) >> 16;   // RNE
    return (short)r;
}
__device__ __forceinline__ float bf2f(short s) {
    return __uint_as_float(((unsigned)(unsigned short)s) << 16);
}

// base-4 digit reversal of a 6-bit index (radix-4 FFT output order)
__device__ __forceinline__ int dr4(int s) {
    return ((s & 3) << 4) | (s & 12) | ((s >> 4) & 3);
}

__device__ __forceinline__ void cmulw(float& xr, float& xi, float wr, float wi) {
    const float tr = xr * wr - xi * wi;
    xi = xr * wi + xi * wr;
    xr = tr;
}

// ---- bf16x4 LDS helpers (fp32 compute, bf16 storage) ----
__device__ __forceinline__ f32x4 ld4bf(const char* Z, int off) {
    const bf16x4 v = *(const bf16x4*)(Z + off);
    f32x4 r;
    r[0] = bf2f(v[0]); r[1] = bf2f(v[1]); r[2] = bf2f(v[2]); r[3] = bf2f(v[3]);
    return r;
}
__device__ __forceinline__ void st4bf(char* Z, int off, f32x4 a) {
    bf16x4 v;
    v[0] = f2bf(a[0]); v[1] = f2bf(a[1]); v[2] = f2bf(a[2]); v[3] = f2bf(a[3]);
    *(bf16x4*)(Z + off) = v;
}

#define DECODE_BCT() \
    const int b  = blockIdx.x >> 8; \
    const int dg = (blockIdx.x >> 2) & 63; \
    const int ct = blockIdx.x & 3;

#define GADDR(slot, blk, f4) \
    (((size_t)(b * 4096 + (slot)) * 512) + (size_t)((blk) * 128 + ct * 32 + (f4) * 4))

#define SETUP_TABLE48() \
    if (tid < 48) { \
        float s_, c_; \
        sincosf(TWO_PI * (float)tid / 64.0f, &s_, &c_); \
        wre[tid] = c_; wim[tid] = -s_; \
    }

// ---------------------------------------------------------------------------
// Radix-4 stages on the MLP A-tile: [64 rows][512B] bf16, re at byte k*2,
// im at byte k*2+256; XOR swizzle ((row&7)<<4) on the column byte.
// Thread: cg = tid&31 (4 channels, byte base cg*8), h = tid>>5 (butterfly).
// Stage math identical to the HW-verified rounds 8-23.
// ---------------------------------------------------------------------------
__device__ __forceinline__ void dif_stage_A(char* Z, const float* wtr, const float* wti,
                                            int cg, int h, int s) {
    const int q  = 16 >> (2 * s);
    const int tw = 1 << (2 * s);
    const int j = h & (q - 1);
    const int g = (s == 0) ? 0 : (h >> (4 - 2 * s));
    const int i0 = g * (q << 2) + j;
    const int i1 = i0 + q, i2 = i1 + q, i3 = i2 + q;
    const int cbR = cg * 8, cbI = cbR + 256;
    const int oR0 = i0 * 512 + (cbR ^ ((i0 & 7) << 4)), oI0 = i0 * 512 + (cbI ^ ((i0 & 7) << 4));
    const int oR1 = i1 * 512 + (cbR ^ ((i1 & 7) << 4)), oI1 = i1 * 512 + (cbI ^ ((i1 & 7) << 4));
    const int oR2 = i2 * 512 + (cbR ^ ((i2 & 7) << 4)), oI2 = i2 * 512 + (cbI ^ ((i2 & 7) << 4));
    const int oR3 = i3 * 512 + (cbR ^ ((i3 & 7) << 4)), oI3 = i3 * 512 + (cbI ^ ((i3 & 7) << 4));
    const f32x4 a0r = ld4bf(Z, oR0), a0i = ld4bf(Z, oI0);
    const f32x4 a1r = ld4bf(Z, oR1), a1i = ld4bf(Z, oI1);
    const f32x4 a2r = ld4bf(Z, oR2), a2i = ld4bf(Z, oI2);
    const f32x4 a3r = ld4bf(Z, oR3), a3i = ld4bf(Z, oI3);
    const int m = j * tw;
    const float w1r = wtr[m],     w1i = wti[m];
    const float w2r = wtr[2 * m], w2i = wti[2 * m];
    const float w3r = wtr[3 * m], w3i = wti[3 * m];
    f32x4 O0r, O0i, O1r, O1i, O2r, O2i, O3r, O3i;
#pragma unroll
    for (int e = 0; e < 4; ++e) {
        const float t0r = a0r[e] + a2r[e], t0i = a0i[e] + a2i[e];
        const float t2r = a0r[e] - a2r[e], t2i = a0i[e] - a2i[e];
        const float t1r = a1r[e] + a3r[e], t1i = a1i[e] + a3i[e];
        const float dr  = a1r[e] - a3r[e], di  = a1i[e] - a3i[e];
        const float t3r = di, t3i = -dr;                 // -i*(a1-a3)
        O0r[e] = t0r + t1r;  O0i[e] = t0i + t1i;
        float y1r = t2r + t3r, y1i = t2i + t3i;
        float y2r = t0r - t1r, y2i = t0i - t1i;
        float y3r = t2r - t3r, y3i = t2i - t3i;
        if (m) {
            cmulw(y1r, y1i, w1r, w1i);
            cmulw(y2r, y2i, w2r, w2i);
            cmulw(y3r, y3i, w3r, w3i);
        }
        O1r[e] = y1r; O1i[e] = y1i;
        O2r[e] = y2r; O2i[e] = y2i;
        O3r[e] = y3r; O3i[e] = y3i;
    }
    st4bf(Z, oR0, O0r);  st4bf(Z, oI0, O0i);
    st4bf(Z, oR1, O1r);  st4bf(Z, oI1, O1i);
    st4bf(Z, oR2, O2r);  st4bf(Z, oI2, O2i);
    st4bf(Z, oR3, O3r);  st4bf(Z, oI3, O3i);
}

__device__ __forceinline__ void dit_stage_A(char* Z, const float* wtr, const float* wti,
                                            int cg, int h, int s) {
    const int q  = 16 >> (2 * s);
    const int tw = 1 << (2 * s);
    const int j = h & (q - 1);
    const int g = (s == 0) ? 0 : (h >> (4 - 2 * s));
    const int i0 = g * (q << 2) + j;
    const int i1 = i0 + q, i2 = i1 + q, i3 = i2 + q;
    const int cbR = cg * 8, cbI = cbR + 256;
    const int oR0 = i0 * 512 + (cbR ^ ((i0 & 7) << 4)), oI0 = i0 * 512 + (cbI ^ ((i0 & 7) << 4));
    const int oR1 = i1 * 512 + (cbR ^ ((i1 & 7) << 4)), oI1 = i1 * 512 + (cbI ^ ((i1 & 7) << 4));
    const int oR2 = i2 * 512 + (cbR ^ ((i2 & 7) << 4)), oI2 = i2 * 512 + (cbI ^ ((i2 & 7) << 4));
    const int oR3 = i3 * 512 + (cbR ^ ((i3 & 7) << 4)), oI3 = i3 * 512 + (cbI ^ ((i3 & 7) << 4));
    const f32x4 a0r = ld4bf(Z, oR0), a0i = ld4bf(Z, oI0);
    const f32x4 a1r = ld4bf(Z, oR1), a1i = ld4bf(Z, oI1);
    const f32x4 a2r = ld4bf(Z, oR2), a2i = ld4bf(Z, oI2);
    const f32x4 a3r = ld4bf(Z, oR3), a3i = ld4bf(Z, oI3);
    const int m = j * tw;
    const float w1r = wtr[m],     w1i = -wti[m];         // conj
    const float w2r = wtr[2 * m], w2i = -wti[2 * m];
    const float w3r = wtr[3 * m], w3i = -wti[3 * m];
    f32x4 O0r, O0i, O1r, O1i, O2r, O2i, O3r, O3i;
#pragma unroll
    for (int e = 0; e < 4; ++e) {
        float b1r = a1r[e], b1i = a1i[e];
        float b2r = a2r[e], b2i = a2i[e];
        float b3r = a3r[e], b3i = a3i[e];
        if (m) {
            cmulw(b1r, b1i, w1r, w1i);
            cmulw(b2r, b2i, w2r, w2i);
            cmulw(b3r, b3i, w3r, w3i);
        }
        const float u0r = a0r[e] + b2r, u0i = a0i[e] + b2i;
        const float u1r = a0r[e] - b2r, u1i = a0i[e] - b2i;
        const float u2r = b1r + b3r,    u2i = b1i + b3i;
        const float dr  = b1r - b3r,    di  = b1i - b3i;
        const float u3r = -di, u3i = dr;                 // +i*(b1-b3)
        O0r[e] = u0r + u2r; O0i[e] = u0i + u2i;
        O1r[e] = u1r + u3r; O1i[e] = u1i + u3i;
        O2r[e] = u0r - u2r; O2i[e] = u0i - u2i;
        O3r[e] = u1r - u3r; O3i[e] = u1i - u3i;
    }
    st4bf(Z, oR0, O0r);  st4bf(Z, oI0, O0i);
    st4bf(Z, oR1, O1r);  st4bf(Z, oI1, O1i);
    st4bf(Z, oR2, O2r);  st4bf(Z, oI2, O2i);
    st4bf(Z, oR3, O3r);  st4bf(Z, oI3, O3i);
}

// ---------------------------------------------------------------------------
// LDS radix-4 64-point FFT, fp16 channel-vectorized (proven R14/R16 core),
// used by fwd_a / inv_b.
// ---------------------------------------------------------------------------
template<int W>
__device__ __forceinline__ void fft64_dif4v(_Float16 (*Lre)[W], _Float16 (*Lim)[W],
                                            const float* wtr, const float* wti,
                                            int c4, int h) {
#pragma unroll
    for (int s = 0; s < 3; ++s) {
        const int q  = 16 >> (2 * s);
        const int tw = 1 << (2 * s);
        __syncthreads();
        const int j = h & (q - 1);
        const int g = (s == 0) ? 0 : (h >> (4 - 2 * s));
        const int i0 = g * (q << 2) + j;
        const int i1 = i0 + q, i2 = i1 + q, i3 = i2 + q;
        const h16x4 A0r = *(const h16x4*)&Lre[i0][c4], A0i = *(const h16x4*)&Lim[i0][c4];
        const h16x4 A1r = *(const h16x4*)&Lre[i1][c4], A1i = *(const h16x4*)&Lim[i1][c4];
        const h16x4 A2r = *(const h16x4*)&Lre[i2][c4], A2i = *(const h16x4*)&Lim[i2][c4];
        const h16x4 A3r = *(const h16x4*)&Lre[i3][c4], A3i = *(const h16x4*)&Lim[i3][c4];
        const int m = j * tw;
        const float w1r = wtr[m],     w1i = wti[m];
        const float w2r = wtr[2 * m], w2i = wti[2 * m];
        const float w3r = wtr[3 * m], w3i = wti[3 * m];
        h16x4 O0r, O0i, O1r, O1i, O2r, O2i, O3r, O3i;
#pragma unroll
        for (int e = 0; e < 4; ++e) {
            const float a0r = (float)A0r[e], a0i = (float)A0i[e];
            const float a1r = (float)A1r[e], a1i = (float)A1i[e];
            const float a2r = (float)A2r[e], a2i = (float)A2i[e];
            const float a3r = (float)A3r[e], a3i = (float)A3i[e];
            const float t0r = a0r + a2r, t0i = a0i + a2i;
            const float t2r = a0r - a2r, t2i = a0i - a2i;
            const float t1r = a1r + a3r, t1i = a1i + a3i;
            const float dr  = a1r - a3r, di  = a1i - a3i;
            const float t3r = di, t3i = -dr;                 // -i*(a1-a3)
            O0r[e] = (_Float16)(t0r + t1r);  O0i[e] = (_Float16)(t0i + t1i);
            float y1r = t2r + t3r, y1i = t2i + t3i;
            float y2r = t0r - t1r, y2i = t0i - t1i;
            float y3r = t2r - t3r, y3i = t2i - t3i;
            if (m) {
                cmulw(y1r, y1i, w1r, w1i);
                cmulw(y2r, y2i, w2r, w2i);
                cmulw(y3r, y3i, w3r, w3i);
            }
            O1r[e] = (_Float16)y1r; O1i[e] = (_Float16)y1i;
            O2r[e] = (_Float16)y2r; O2i[e] = (_Float16)y2i;
            O3r[e] = (_Float16)y3r; O3i[e] = (_Float16)y3i;
        }
        *(h16x4*)&Lre[i0][c4] = O0r;  *(h16x4*)&Lim[i0][c4] = O0i;
        *(h16x4*)&Lre[i1][c4] = O1r;  *(h16x4*)&Lim[i1][c4] = O1i;
        *(h16x4*)&Lre[i2][c4] = O2r;  *(h16x4*)&Lim[i2][c4] = O2i;
        *(h16x4*)&Lre[i3][c4] = O3r;  *(h16x4*)&Lim[i3][c4] = O3i;
    }
    __syncthreads();
}

template<int W>
__device__ __forceinline__ void fft64_dit4v(_Float16 (*Lre)[W], _Float16 (*Lim)[W],
                                            const float* wtr, const float* wti,
                                            int c4, int h) {
#pragma unroll
    for (int s = 2; s >= 0; --s) {
        const int q  = 16 >> (2 * s);
        const int tw = 1 << (2 * s);
        __syncthreads();
        const int j = h & (q - 1);
        const int g = (s == 0) ? 0 : (h >> (4 - 2 * s));
        const int i0 = g * (q << 2) + j;
        const int i1 = i0 + q, i2 = i1 + q, i3 = i2 + q;
        const h16x4 A0r = *(const h16x4*)&Lre[i0][c4], A0i = *(const h16x4*)&Lim[i0][c4];
        const h16x4 A1r = *(const h16x4*)&Lre[i1][c4], A1i = *(const h16x4*)&Lim[i1][c4];
        const h16x4 A2r = *(const h16x4*)&Lre[i2][c4], A2i = *(const h16x4*)&Lim[i2][c4];
        const h16x4 A3r = *(const h16x4*)&Lre[i3][c4], A3i = *(const h16x4*)&Lim[i3][c4];
        const int m = j * tw;
        const float w1r = wtr[m],     w1i = -wti[m];         // conj
        const float w2r = wtr[2 * m], w2i = -wti[2 * m];
        const float w3r = wtr[3 * m], w3i = -wti[3 * m];
        h16x4 O0r, O0i, O1r, O1i, O2r, O2i, O3r, O3i;
#pragma unroll
        for (int e = 0; e < 4; ++e) {
            float b1r = (float)A1r[e], b1i = (float)A1i[e];
            float b2r = (float)A2r[e], b2i = (float)A2i[e];
            float b3r = (float)A3r[e], b3i = (float)A3i[e];
            if (m) {
                cmulw(b1r, b1i, w1r, w1i);
                cmulw(b2r, b2i, w2r, w2i);
                cmulw(b3r, b3i, w3r, w3i);
            }
            const float a0r = (float)A0r[e], a0i = (float)A0i[e];
            const float u0r = a0r + b2r, u0i = a0i + b2i;
            const float u1r = a0r - b2r, u1i = a0i - b2i;
            const float u2r = b1r + b3r, u2i = b1i + b3i;
            const float dr  = b1r - b3r, di  = b1i - b3i;
            const float u3r = -di, u3i = dr;                 // +i*(b1-b3)
            O0r[e] = (_Float16)(u0r + u2r); O0i[e] = (_Float16)(u0i + u2i);
            O1r[e] = (_Float16)(u1r + u3r); O1i[e] = (_Float16)(u1i + u3i);
            O2r[e] = (_Float16)(u0r - u2r); O2i[e] = (_Float16)(u0i - u2i);
            O3r[e] = (_Float16)(u1r - u3r); O3i[e] = (_Float16)(u1i - u3i);
        }
        *(h16x4*)&Lre[i0][c4] = O0r;  *(h16x4*)&Lim[i0][c4] = O0i;
        *(h16x4*)&Lre[i1][c4] = O1r;  *(h16x4*)&Lim[i1][c4] = O1i;
        *(h16x4*)&Lre[i2][c4] = O2r;  *(h16x4*)&Lim[i2][c4] = O2i;
        *(h16x4*)&Lre[i3][c4] = O3r;  *(h16x4*)&Lim[i3][c4] = O3i;
    }
    __syncthreads();
}

// ---- forward pass A: FFT over n1, twiddle, FUSED fft4_fwd (x1/128),
// x fp32 -> z bf16 (unchanged from passing rounds 16-23)
extern "C" __global__ void __launch_bounds__(512)
fft_fwd_a(const float* __restrict__ x, short* __restrict__ zre, short* __restrict__ zim) {
    __shared__ __align__(16) _Float16 Lre[64][136];
    __shared__ __align__(16) _Float16 Lim[64][136];
    __shared__ float wre[48], wim[48];
    __shared__ float twr[64], twi[64];
    const int tid = threadIdx.x;
    SETUP_TABLE48();
    DECODE_BCT();   // dg = n2
    if (tid >= 64 && tid < 128) {
        const int s1 = tid - 64;
        float sn, cs;
        sincosf(-(TWO_PI / 4096.0f) * (float)(dg * dr4(s1)), &sn, &cs);
        twr[s1] = cs; twi[s1] = sn;
    }
    for (int idx = tid; idx < 2048; idx += 512) {
        const int n1 = idx >> 5, q = idx & 31, blk = q >> 3, f4 = q & 7;
        const int cl = blk * 32 + f4 * 4;
        const float4 v = *(const float4*)(x + GADDR(n1 * 64 + dg, blk, f4));
        h16x4 hv, hz;
        hv[0] = (_Float16)v.x; hv[1] = (_Float16)v.y;
        hv[2] = (_Float16)v.z; hv[3] = (_Float16)v.w;
        hz[0] = (_Float16)0.f; hz[1] = (_Float16)0.f;
        hz[2] = (_Float16)0.f; hz[3] = (_Float16)0.f;
        *(h16x4*)&Lre[n1][cl] = hv;
        *(h16x4*)&Lim[n1][cl] = hz;
    }
    fft64_dif4v<136>(Lre, Lim, wre, wim, (tid & 31) * 4, tid >> 5);
    {
        const int s1 = tid >> 3, f4 = tid & 7;
        const float cs = twr[s1], sn = twi[s1];
        f32x4 r[4], m[4];
#pragma unroll
        for (int blk = 0; blk < 4; ++blk) {
            const int cl = blk * 32 + f4 * 4;
            const h16x4 hr = *(const h16x4*)&Lre[s1][cl];
            const h16x4 hi = *(const h16x4*)&Lim[s1][cl];
#pragma unroll
            for (int e = 0; e < 4; ++e) {
                const float vr = (float)hr[e], vi = (float)hi[e];
                r[blk][e] = vr * cs - vi * sn;
                m[blk][e] = vr * sn + vi * cs;
            }
        }
        const float sc = 1.0f / 128.0f;
        f32x4 yr[4], ym[4];
#pragma unroll
        for (int e = 0; e < 4; ++e) {
            const float r0 = r[0][e], r1 = r[1][e], r2 = r[2][e], r3 = r[3][e];
            const float m0 = m[0][e], m1 = m[1][e], m2 = m[2][e], m3 = m[3][e];
            yr[0][e] = (r0 + r1 + r2 + r3) * sc;  ym[0][e] = (m0 + m1 + m2 + m3) * sc;
            yr[1][e] = (r0 + m1 - r2 - m3) * sc;  ym[1][e] = (m0 - r1 - m2 + r3) * sc;
            yr[2][e] = (r0 - r1 + r2 - r3) * sc;  ym[2][e] = (m0 - m1 + m2 - m3) * sc;
            yr[3][e] = (r0 - m1 - r2 + m3) * sc;  ym[3][e] = (m0 + r1 - m2 - r3) * sc;
        }
#pragma unroll
        for (int blk = 0; blk < 4; ++blk) {
            bf16x4 pr, pi;
#pragma unroll
            for (int e = 0; e < 4; ++e) {
                pr[e] = f2bf(yr[blk][e]);
                pi[e] = f2bf(ym[blk][e]);
            }
            const size_t g = GADDR(s1 * 64 + dg, blk, f4);
            *(bf16x4*)(zre + g) = pr;
            *(bf16x4*)(zim + g) = pi;
        }
    }
}

// ---- inverse pass B: inverse twiddle (table) + FUSED ifft4 (x1/128) on
// load, inverse FFT over k1, write REAL fp32 into d_out (unchanged R20-23)
extern "C" __global__ void __launch_bounds__(512)
fft_inv_b(const short* __restrict__ zre, const short* __restrict__ zim,
          float* __restrict__ out) {
    __shared__ __align__(16) _Float16 Lre[64][136];
    __shared__ __align__(16) _Float16 Lim[64][136];
    __shared__ float wre[48], wim[48];
    __shared__ float twr[64], twi[64];
    const int tid = threadIdx.x;
    SETUP_TABLE48();
    DECODE_BCT();   // dg = n2
    if (tid >= 64 && tid < 128) {
        const int s1 = tid - 64;
        float sn, cs;
        sincosf((TWO_PI / 4096.0f) * (float)(dg * dr4(s1)), &sn, &cs);
        twr[s1] = cs; twi[s1] = sn;
    }
    __syncthreads();   // twiddle table ready before the load sweep uses it
    {
        const int s1 = tid >> 3, f4 = tid & 7;
        const float cs = twr[s1], sn = twi[s1];
        f32x4 r[4], m[4];
#pragma unroll
        for (int blk = 0; blk < 4; ++blk) {
            const size_t g = GADDR(s1 * 64 + dg, blk, f4);
            const bf16x4 vr = *(const bf16x4*)(zre + g);
            const bf16x4 vi = *(const bf16x4*)(zim + g);
#pragma unroll
            for (int e = 0; e < 4; ++e) {
                const float ar = bf2f(vr[e]), ai = bf2f(vi[e]);
                r[blk][e] = ar * cs - ai * sn;
                m[blk][e] = ar * sn + ai * cs;
            }
        }
        const float sc = 1.0f / 128.0f;
        f32x4 yr[4], ym[4];
#pragma unroll
        for (int e = 0; e < 4; ++e) {
            const float r0 = r[0][e], r1 = r[1][e], r2 = r[2][e], r3 = r[3][e];
            const float m0 = m[0][e], m1 = m[1][e], m2 = m[2][e], m3 = m[3][e];
            yr[0][e] = (r0 + r1 + r2 + r3) * sc;  ym[0][e] = (m0 + m1 + m2 + m3) * sc;
            yr[1][e] = (r0 - m1 - r2 + m3) * sc;  ym[1][e] = (m0 + r1 - m2 - r3) * sc;
            yr[2][e] = (r0 - r1 + r2 - r3) * sc;  ym[2][e] = (m0 - m1 + m2 - m3) * sc;
            yr[3][e] = (r0 + m1 - r2 - m3) * sc;  ym[3][e] = (m0 - r1 - m2 + r3) * sc;
        }
#pragma unroll
        for (int blk = 0; blk < 4; ++blk) {
            const int cl = blk * 32 + f4 * 4;
            h16x4 hr, hi;
#pragma unroll
            for (int e = 0; e < 4; ++e) {
                hr[e] = (_Float16)yr[blk][e];
                hi[e] = (_Float16)ym[blk][e];
            }
            *(h16x4*)&Lre[s1][cl] = hr;
            *(h16x4*)&Lim[s1][cl] = hi;
        }
    }
    fft64_dit4v<136>(Lre, Lim, wre, wim, (tid & 31) * 4, tid >> 5);
    for (int idx = tid; idx < 2048; idx += 512) {
        const int n1 = idx >> 5, q = idx & 31, blk = q >> 3, f4 = q & 7;
        const int cl = blk * 32 + f4 * 4;
        const h16x4 hr = *(const h16x4*)&Lre[n1][cl];
        float4 o;
        o.x = (float)hr[0]; o.y = (float)hr[1];
        o.z = (float)hr[2]; o.w = (float)hr[3];
        *(float4*)(out + GADDR(n1 * 64 + dg, blk, f4)) = o;
    }
}

// ---------------------------------------------------------------------------
// Weight prep: fold complex 2x2 into W_big bf16 [L][blk][n][k], in d_out.
// ---------------------------------------------------------------------------
extern "C" __global__ void __launch_bounds__(256)
wprep(const float* __restrict__ w1, const float* __restrict__ w2,
      short* __restrict__ wb) {
    const int i4  = blockIdx.x * 256 + threadIdx.x;
    const int k0  = (i4 & 63) * 4;
    const int n   = (i4 >> 6) & 255;
    const int blk = (i4 >> 14) & 3;
    const int L   = i4 >> 16;
    const float* w = L ? w2 : w1;
    bf16x4 pv;
#pragma unroll
    for (int j = 0; j < 4; ++j) {
        const int k = k0 + j;
        float v;
        if (k < 128) {
            v = (n < 128) ? w[blk * 16384 + k * 128 + n]
                          : w[65536 + blk * 16384 + k * 128 + (n - 128)];
        } else {
            v = (n < 128) ? -w[65536 + blk * 16384 + (k - 128) * 128 + n]
                          :  w[blk * 16384 + (k - 128) * 128 + (n - 128)];
        }
        pv[j] = f2bf(v);
    }
    *(bf16x4*)(wb + (size_t)i4 * 4) = pv;
}

// ---------------------------------------------------------------------------
// FUSED MFMA MLP layer + n2-FFT, in place. MITER=2: 1024 blocks per kernel
// (2x the 2-blocks/CU x 256-CU capacity) so retiring blocks are backfilled
// and fresh blocks' stage_tile fills overlap other blocks' compute.
// ---------------------------------------------------------------------------
#define MITER 2

__device__ __forceinline__ void stage_tile(const short* __restrict__ zre,
                                           const short* __restrict__ zim,
                                           char* Abuf, int rowbase, int blk,
                                           int wave, int lane) {
#pragma unroll
    for (int it = 0; it < 4; ++it) {
        const int chunk = wave * 256 + it * 64 + lane;   // 16B chunk id, 0..2047
        const int row   = chunk >> 5;
        const unsigned kbyte = ((unsigned)((chunk & 31) << 4)) ^ ((unsigned)((row & 7) << 4));
        const int k0 = (int)(kbyte >> 1);                // element k, multiple of 8
        const short* src = (k0 < 128) ? zre : zim;
        const size_t g = (size_t)(rowbase + row) * 512 + blk * 128 + (k0 & 127);
        unsigned* lp = (unsigned*)(Abuf + (wave * 4096 + it * 1024));  // wave-uniform
        __builtin_amdgcn_global_load_lds((const unsigned*)(src + g), lp, 16, 0, 0);
    }
}

template<int LAYER>
__global__ void __launch_bounds__(512)
mlp_fused(short* __restrict__ zre, short* __restrict__ zim,
          const short* __restrict__ wb, const float* __restrict__ bias) {
    __shared__ __align__(16) char As[2][64 * 256 * 2];   // 2 x 32 KB bf16, swizzled
    __shared__ float wre[48], wim[48];

    const int blk  = blockIdx.y;
    const int tid  = threadIdx.x;
    const int wave = tid >> 6;
    const int lane = tid & 63;
    const int lrow = lane & 15;
    const int lk   = lane >> 4;
    const int cg   = tid & 31;     // FFT: 4-channel group
    const int fh   = tid >> 5;     // FFT: butterfly index 0..15
    SETUP_TABLE48();

    bf16x8 Bf[2][8];
#pragma unroll
    for (int nt = 0; nt < 2; ++nt) {
        const int n = wave * 32 + nt * 16 + lrow;
#pragma unroll
        for (int ks = 0; ks < 8; ++ks) {
            Bf[nt][ks] = *(const bf16x8*)(wb + ((size_t)(blk * 256 + n) * 256 + ks * 32 + lk * 8));
        }
    }

    // bias for the 4 consecutive n this lane owns per fragment (swapped layout)
    f32x4 bv4[2];
#pragma unroll
    for (int nt = 0; nt < 2; ++nt) {
        const int n0 = wave * 32 + nt * 16 + lk * 4;
        const float* bp = bias + ((n0 < 128) ? (blk * 128 + n0)
                                             : (512 + blk * 128 + (n0 - 128)));
        bv4[nt] = *(const f32x4*)bp;
    }

    stage_tile(zre, zim, As[0], blockIdx.x * MITER * 64, blk, wave, lane);

    for (int t = 0; t < MITER; ++t) {
        __syncthreads();   // staged tile t visible

        char* Ab = As[t & 1];
        const int rowbase = (blockIdx.x * MITER + t) * 64;

        if (LAYER == 1) {
            // ---- forward n2-FFT on the staged tile (cols = channels)
            dif_stage_A(Ab, wre, wim, cg, fh, 0);
            __syncthreads();
            dif_stage_A(Ab, wre, wim, cg, fh, 1);
            __syncthreads();
            dif_stage_A(Ab, wre, wim, cg, fh, 2);
            __syncthreads();
        }

        if (t + 1 < MITER)
            stage_tile(zre, zim, As[(t + 1) & 1],
                       (blockIdx.x * MITER + t + 1) * 64, blk, wave, lane);

        f32x4 acc[4][2];
#pragma unroll
        for (int mt = 0; mt < 4; ++mt)
#pragma unroll
            for (int nt = 0; nt < 2; ++nt)
                acc[mt][nt] = (f32x4){0.f, 0.f, 0.f, 0.f};

#pragma unroll
        for (int ks = 0; ks < 8; ++ks) {
            bf16x8 af[4];
#pragma unroll
            for (int mt = 0; mt < 4; ++mt) {
                const int row = mt * 16 + lrow;
                const int k0  = ks * 32 + lk * 8;
                const unsigned byteoff =
                    ((unsigned)(row * 512 + k0 * 2)) ^ ((unsigned)((row & 7) << 4));
                af[mt] = *(const bf16x8*)(Ab + byteoff);
            }
            // operand-swapped: D = Bf(A-op) x af(B-op) = (A*W)^T
#pragma unroll
            for (int mt = 0; mt < 4; ++mt)
#pragma unroll
                for (int nt = 0; nt < 2; ++nt)
                    acc[mt][nt] = __builtin_amdgcn_mfma_f32_16x16x32_bf16(
                        Bf[nt][ks], af[mt], acc[mt][nt], 0, 0, 0);
        }

        if (LAYER == 1) {
            // ---- relu + bias, vectorized store (lane: row = mt*16+lrow,
            //      n = wave*32 + nt*16 + lk*4 + r)
#pragma unroll
            for (int nt = 0; nt < 2; ++nt) {
                const int n0 = wave * 32 + nt * 16 + lk * 4;
                short* dst = (n0 < 128) ? zre : zim;
                const int colb = blk * 128 + (n0 & 127);
#pragma unroll
                for (int mt = 0; mt < 4; ++mt) {
                    const int row = rowbase + mt * 16 + lrow;
                    bf16x4 pv;
#pragma unroll
                    for (int r = 0; r < 4; ++r)
                        pv[r] = f2bf(fmaxf(acc[mt][nt][r] + bv4[nt][r], 0.0f));
                    *(bf16x4*)(dst + (size_t)row * 512 + colb) = pv;
                }
            }
        } else {
            // ---- softshrink + bias, vectorized write into LDS tile
            __syncthreads();   // all MFMA reads of Ab complete
#pragma unroll
            for (int nt = 0; nt < 2; ++nt) {
                const int n0 = wave * 32 + nt * 16 + lk * 4;
                const int cb = n0 * 2;     // byte col: re 0..255, im 256..511
#pragma unroll
                for (int mt = 0; mt < 4; ++mt) {
                    const int row = mt * 16 + lrow;
                    bf16x4 pv;
#pragma unroll
                    for (int r = 0; r < 4; ++r) {
                        float v = acc[mt][nt][r] + bv4[nt][r];
                        v = (v > 0.01f) ? v - 0.01f : ((v < -0.01f) ? v + 0.01f : 0.0f);
                        pv[r] = f2bf(v);
                    }
                    *(bf16x4*)(Ab + row * 512 + (cb ^ ((row & 7) << 4))) = pv;
                }
            }
            __syncthreads();
            dit_stage_A(Ab, wre, wim, cg, fh, 2);
            __syncthreads();
            dit_stage_A(Ab, wre, wim, cg, fh, 1);
            __syncthreads();
            dit_stage_A(Ab, wre, wim, cg, fh, 0);
            __syncthreads();
            // ---- PLAIN de-swizzle store (rows natural n2; twiddle in inv_b)
#pragma unroll
            for (int kk = 0; kk < 4; ++kk) {
                const int idx = tid + kk * 512;    // 2048 = 64 rows x 2 planes x 16 chunks
                const int row = idx >> 5;
                const int q = idx & 31;
                const int p = q >> 4;              // 0 = re, 1 = im
                const int c = q & 15;              // 8-ch chunk within 128-ch window
                const int cbyte = p * 256 + c * 16;
                const bf16x8 v = *(const bf16x8*)(Ab + row * 512 + (cbyte ^ ((row & 7) << 4)));
                short* dst = p ? zim : zre;
                *(bf16x8*)(dst + (size_t)(rowbase + row) * 512 + blk * 128 + c * 8) = v;
            }
        }
    }
}

extern "C" void kernel_launch(void* const* d_in, const int* in_sizes, int n_in,
                              void* d_out, int out_size, void* d_ws, size_t ws_size,
                              hipStream_t stream) {
    const float* x  = (const float*)d_in[0];
    const float* w1 = (const float*)d_in[1];
    const float* w2 = (const float*)d_in[2];
    const float* b1 = (const float*)d_in[3];
    const float* b2 = (const float*)d_in[4];

    float* out = (float*)d_out;
    short* zre = (short*)d_ws;            // bf16 real plane, 32 MiB
    short* zim = zre + 16777216;          // bf16 imag plane, 32 MiB
    short* wb  = (short*)d_out;           // 1 MiB W_big scratch inside d_out
    const size_t WB_L = 4ull * 256 * 256;

    wprep<<<512, 256, 0, stream>>>(w1, w2, wb);

    // forward: pass A (n1-FFT + twiddle + fft4); n2-FFT fused into MLP layer 1
    fft_fwd_a<<<2048, 512, 0, stream>>>(x, zre, zim);

    mlp_fused<1><<<dim3(32768 / (64 * MITER), 4), 512, 0, stream>>>(zre, zim, wb, b1);
    mlp_fused<2><<<dim3(32768 / (64 * MITER), 4), 512, 0, stream>>>(zre, zim, wb + WB_L, b2);

    // inverse: inverse n2-FFT fused into MLP layer 2; inv_b applies the
    // inverse twiddle + ifft4 on load, then finishes over k1
    fft_inv_b<<<2048, 512, 0, stream>>>(zre, zim, out);
}

// Round 25
// 192.956 us; speedup vs baseline: 1.1018x; 1.1018x over previous
//
#include <hip/hip_runtime.h>
#include <math.h>

#define TWO_PI 6.283185307179586f

typedef __attribute__((ext_vector_type(8))) short bf16x8;
typedef __attribute__((ext_vector_type(4))) short bf16x4;
typedef __attribute__((ext_vector_type(4))) float f32x4;
typedef __attribute__((ext_vector_type(4))) _Float16 h16x4;
typedef __attribute__((ext_vector_type(8))) _Float16 h16x8;

__device__ __forceinline__ short f2bf(float f) {
    unsigned u = __float_as_uint(f);
    unsigned r = (u + 0x7FFFu + ((u >> 16) & 1u)) >> 16;   // RNE
    return (short)r;
}
__device__ __forceinline__ float bf2f(short s) {
    return __uint_as_float(((unsigned)(unsigned short)s) << 16);
}

// base-4 digit reversal of a 6-bit index (radix-4 FFT output order)
__device__ __forceinline__ int dr4(int s) {
    return ((s & 3) << 4) | (s & 12) | ((s >> 4) & 3);
}

__device__ __forceinline__ void cmulw(float& xr, float& xi, float wr, float wi) {
    const float tr = xr * wr - xi * wi;
    xi = xr * wi + xi * wr;
    xr = tr;
}

// ---- bf16x4 LDS helpers (fp32 compute, bf16 storage) ----
__device__ __forceinline__ f32x4 ld4bf(const char* Z, int off) {
    const bf16x4 v = *(const bf16x4*)(Z + off);
    f32x4 r;
    r[0] = bf2f(v[0]); r[1] = bf2f(v[1]); r[2] = bf2f(v[2]); r[3] = bf2f(v[3]);
    return r;
}
__device__ __forceinline__ void st4bf(char* Z, int off, f32x4 a) {
    bf16x4 v;
    v[0] = f2bf(a[0]); v[1] = f2bf(a[1]); v[2] = f2bf(a[2]); v[3] = f2bf(a[3]);
    *(bf16x4*)(Z + off) = v;
}

#define DECODE_BCT() \
    const int b  = blockIdx.x >> 8; \
    const int dg = (blockIdx.x >> 2) & 63; \
    const int ct = blockIdx.x & 3;

#define GADDR(slot, blk, f4) \
    (((size_t)(b * 4096 + (slot)) * 512) + (size_t)((blk) * 128 + ct * 32 + (f4) * 4))

#define SETUP_TABLE48() \
    if (tid < 48) { \
        float s_, c_; \
        sincosf(TWO_PI * (float)tid / 64.0f, &s_, &c_); \
        wre[tid] = c_; wim[tid] = -s_; \
    }

// ---------------------------------------------------------------------------
// Radix-4 stages on the MLP A-tile: [64 rows][512B] bf16, re at byte k*2,
// im at byte k*2+256; XOR swizzle ((row&7)<<4) on the column byte.
// Thread: cg = tid&31 (4 channels, byte base cg*8), h = tid>>5 (butterfly).
// Stage math identical to the HW-verified rounds 8-23.
// ---------------------------------------------------------------------------
__device__ __forceinline__ void dif_stage_A(char* Z, const float* wtr, const float* wti,
                                            int cg, int h, int s) {
    const int q  = 16 >> (2 * s);
    const int tw = 1 << (2 * s);
    const int j = h & (q - 1);
    const int g = (s == 0) ? 0 : (h >> (4 - 2 * s));
    const int i0 = g * (q << 2) + j;
    const int i1 = i0 + q, i2 = i1 + q, i3 = i2 + q;
    const int cbR = cg * 8, cbI = cbR + 256;
    const int oR0 = i0 * 512 + (cbR ^ ((i0 & 7) << 4)), oI0 = i0 * 512 + (cbI ^ ((i0 & 7) << 4));
    const int oR1 = i1 * 512 + (cbR ^ ((i1 & 7) << 4)), oI1 = i1 * 512 + (cbI ^ ((i1 & 7) << 4));
    const int oR2 = i2 * 512 + (cbR ^ ((i2 & 7) << 4)), oI2 = i2 * 512 + (cbI ^ ((i2 & 7) << 4));
    const int oR3 = i3 * 512 + (cbR ^ ((i3 & 7) << 4)), oI3 = i3 * 512 + (cbI ^ ((i3 & 7) << 4));
    const f32x4 a0r = ld4bf(Z, oR0), a0i = ld4bf(Z, oI0);
    const f32x4 a1r = ld4bf(Z, oR1), a1i = ld4bf(Z, oI1);
    const f32x4 a2r = ld4bf(Z, oR2), a2i = ld4bf(Z, oI2);
    const f32x4 a3r = ld4bf(Z, oR3), a3i = ld4bf(Z, oI3);
    const int m = j * tw;
    const float w1r = wtr[m],     w1i = wti[m];
    const float w2r = wtr[2 * m], w2i = wti[2 * m];
    const float w3r = wtr[3 * m], w3i = wti[3 * m];
    f32x4 O0r, O0i, O1r, O1i, O2r, O2i, O3r, O3i;
#pragma unroll
    for (int e = 0; e < 4; ++e) {
        const float t0r = a0r[e] + a2r[e], t0i = a0i[e] + a2i[e];
        const float t2r = a0r[e] - a2r[e], t2i = a0i[e] - a2i[e];
        const float t1r = a1r[e] + a3r[e], t1i = a1i[e] + a3i[e];
        const float dr  = a1r[e] - a3r[e], di  = a1i[e] - a3i[e];
        const float t3r = di, t3i = -dr;                 // -i*(a1-a3)
        O0r[e] = t0r + t1r;  O0i[e] = t0i + t1i;
        float y1r = t2r + t3r, y1i = t2i + t3i;
        float y2r = t0r - t1r, y2i = t0i - t1i;
        float y3r = t2r - t3r, y3i = t2i - t3i;
        if (m) {
            cmulw(y1r, y1i, w1r, w1i);
            cmulw(y2r, y2i, w2r, w2i);
            cmulw(y3r, y3i, w3r, w3i);
        }
        O1r[e] = y1r; O1i[e] = y1i;
        O2r[e] = y2r; O2i[e] = y2i;
        O3r[e] = y3r; O3i[e] = y3i;
    }
    st4bf(Z, oR0, O0r);  st4bf(Z, oI0, O0i);
    st4bf(Z, oR1, O1r);  st4bf(Z, oI1, O1i);
    st4bf(Z, oR2, O2r);  st4bf(Z, oI2, O2i);
    st4bf(Z, oR3, O3r);  st4bf(Z, oI3, O3i);
}

__device__ __forceinline__ void dit_stage_A(char* Z, const float* wtr, const float* wti,
                                            int cg, int h, int s) {
    const int q  = 16 >> (2 * s);
    const int tw = 1 << (2 * s);
    const int j = h & (q - 1);
    const int g = (s == 0) ? 0 : (h >> (4 - 2 * s));
    const int i0 = g * (q << 2) + j;
    const int i1 = i0 + q, i2 = i1 + q, i3 = i2 + q;
    const int cbR = cg * 8, cbI = cbR + 256;
    const int oR0 = i0 * 512 + (cbR ^ ((i0 & 7) << 4)), oI0 = i0 * 512 + (cbI ^ ((i0 & 7) << 4));
    const int oR1 = i1 * 512 + (cbR ^ ((i1 & 7) << 4)), oI1 = i1 * 512 + (cbI ^ ((i1 & 7) << 4));
    const int oR2 = i2 * 512 + (cbR ^ ((i2 & 7) << 4)), oI2 = i2 * 512 + (cbI ^ ((i2 & 7) << 4));
    const int oR3 = i3 * 512 + (cbR ^ ((i3 & 7) << 4)), oI3 = i3 * 512 + (cbI ^ ((i3 & 7) << 4));
    const f32x4 a0r = ld4bf(Z, oR0), a0i = ld4bf(Z, oI0);
    const f32x4 a1r = ld4bf(Z, oR1), a1i = ld4bf(Z, oI1);
    const f32x4 a2r = ld4bf(Z, oR2), a2i = ld4bf(Z, oI2);
    const f32x4 a3r = ld4bf(Z, oR3), a3i = ld4bf(Z, oI3);
    const int m = j * tw;
    const float w1r = wtr[m],     w1i = -wti[m];         // conj
    const float w2r = wtr[2 * m], w2i = -wti[2 * m];
    const float w3r = wtr[3 * m], w3i = -wti[3 * m];
    f32x4 O0r, O0i, O1r, O1i, O2r, O2i, O3r, O3i;
#pragma unroll
    for (int e = 0; e < 4; ++e) {
        float b1r = a1r[e], b1i = a1i[e];
        float b2r = a2r[e], b2i = a2i[e];
        float b3r = a3r[e], b3i = a3i[e];
        if (m) {
            cmulw(b1r, b1i, w1r, w1i);
            cmulw(b2r, b2i, w2r, w2i);
            cmulw(b3r, b3i, w3r, w3i);
        }
        const float u0r = a0r[e] + b2r, u0i = a0i[e] + b2i;
        const float u1r = a0r[e] - b2r, u1i = a0i[e] - b2i;
        const float u2r = b1r + b3r,    u2i = b1i + b3i;
        const float dr  = b1r - b3r,    di  = b1i - b3i;
        const float u3r = -di, u3i = dr;                 // +i*(b1-b3)
        O0r[e] = u0r + u2r; O0i[e] = u0i + u2i;
        O1r[e] = u1r + u3r; O1i[e] = u1i + u3i;
        O2r[e] = u0r - u2r; O2i[e] = u0i - u2i;
        O3r[e] = u1r - u3r; O3i[e] = u1i - u3i;
    }
    st4bf(Z, oR0, O0r);  st4bf(Z, oI0, O0i);
    st4bf(Z, oR1, O1r);  st4bf(Z, oI1, O1i);
    st4bf(Z, oR2, O2r);  st4bf(Z, oI2, O2i);
    st4bf(Z, oR3, O3r);  st4bf(Z, oI3, O3i);
}

// ---------------------------------------------------------------------------
// LDS radix-4 64-point FFT, fp16 channel-vectorized (proven R14/R16 core),
// used by fwd_a / inv_b.
// ---------------------------------------------------------------------------
template<int W>
__device__ __forceinline__ void fft64_dif4v(_Float16 (*Lre)[W], _Float16 (*Lim)[W],
                                            const float* wtr, const float* wti,
                                            int c4, int h) {
#pragma unroll
    for (int s = 0; s < 3; ++s) {
        const int q  = 16 >> (2 * s);
        const int tw = 1 << (2 * s);
        __syncthreads();
        const int j = h & (q - 1);
        const int g = (s == 0) ? 0 : (h >> (4 - 2 * s));
        const int i0 = g * (q << 2) + j;
        const int i1 = i0 + q, i2 = i1 + q, i3 = i2 + q;
        const h16x4 A0r = *(const h16x4*)&Lre[i0][c4], A0i = *(const h16x4*)&Lim[i0][c4];
        const h16x4 A1r = *(const h16x4*)&Lre[i1][c4], A1i = *(const h16x4*)&Lim[i1][c4];
        const h16x4 A2r = *(const h16x4*)&Lre[i2][c4], A2i = *(const h16x4*)&Lim[i2][c4];
        const h16x4 A3r = *(const h16x4*)&Lre[i3][c4], A3i = *(const h16x4*)&Lim[i3][c4];
        const int m = j * tw;
        const float w1r = wtr[m],     w1i = wti[m];
        const float w2r = wtr[2 * m], w2i = wti[2 * m];
        const float w3r = wtr[3 * m], w3i = wti[3 * m];
        h16x4 O0r, O0i, O1r, O1i, O2r, O2i, O3r, O3i;
#pragma unroll
        for (int e = 0; e < 4; ++e) {
            const float a0r = (float)A0r[e], a0i = (float)A0i[e];
            const float a1r = (float)A1r[e], a1i = (float)A1i[e];
            const float a2r = (float)A2r[e], a2i = (float)A2i[e];
            const float a3r = (float)A3r[e], a3i = (float)A3i[e];
            const float t0r = a0r + a2r, t0i = a0i + a2i;
            const float t2r = a0r - a2r, t2i = a0i - a2i;
            const float t1r = a1r + a3r, t1i = a1i + a3i;
            const float dr  = a1r - a3r, di  = a1i - a3i;
            const float t3r = di, t3i = -dr;                 // -i*(a1-a3)
            O0r[e] = (_Float16)(t0r + t1r);  O0i[e] = (_Float16)(t0i + t1i);
            float y1r = t2r + t3r, y1i = t2i + t3i;
            float y2r = t0r - t1r, y2i = t0i - t1i;
            float y3r = t2r - t3r, y3i = t2i - t3i;
            if (m) {
                cmulw(y1r, y1i, w1r, w1i);
                cmulw(y2r, y2i, w2r, w2i);
                cmulw(y3r, y3i, w3r, w3i);
            }
            O1r[e] = (_Float16)y1r; O1i[e] = (_Float16)y1i;
            O2r[e] = (_Float16)y2r; O2i[e] = (_Float16)y2i;
            O3r[e] = (_Float16)y3r; O3i[e] = (_Float16)y3i;
        }
        *(h16x4*)&Lre[i0][c4] = O0r;  *(h16x4*)&Lim[i0][c4] = O0i;
        *(h16x4*)&Lre[i1][c4] = O1r;  *(h16x4*)&Lim[i1][c4] = O1i;
        *(h16x4*)&Lre[i2][c4] = O2r;  *(h16x4*)&Lim[i2][c4] = O2i;
        *(h16x4*)&Lre[i3][c4] = O3r;  *(h16x4*)&Lim[i3][c4] = O3i;
    }
    __syncthreads();
}

template<int W>
__device__ __forceinline__ void fft64_dit4v(_Float16 (*Lre)[W], _Float16 (*Lim)[W],
                                            const float* wtr, const float* wti,
                                            int c4, int h) {
#pragma unroll
    for (int s = 2; s >= 0; --s) {
        const int q  = 16 >> (2 * s);
        const int tw = 1 << (2 * s);
        __syncthreads();
        const int j = h & (q - 1);
        const int g = (s == 0) ? 0 : (h >> (4 - 2 * s));
        const int i0 = g * (q << 2) + j;
        const int i1 = i0 + q, i2 = i1 + q, i3 = i2 + q;
        const h16x4 A0r = *(const h16x4*)&Lre[i0][c4], A0i = *(const h16x4*)&Lim[i0][c4];
        const h16x4 A1r = *(const h16x4*)&Lre[i1][c4], A1i = *(const h16x4*)&Lim[i1][c4];
        const h16x4 A2r = *(const h16x4*)&Lre[i2][c4], A2i = *(const h16x4*)&Lim[i2][c4];
        const h16x4 A3r = *(const h16x4*)&Lre[i3][c4], A3i = *(const h16x4*)&Lim[i3][c4];
        const int m = j * tw;
        const float w1r = wtr[m],     w1i = -wti[m];         // conj
        const float w2r = wtr[2 * m], w2i = -wti[2 * m];
        const float w3r = wtr[3 * m], w3i = -wti[3 * m];
        h16x4 O0r, O0i, O1r, O1i, O2r, O2i, O3r, O3i;
#pragma unroll
        for (int e = 0; e < 4; ++e) {
            float b1r = (float)A1r[e], b1i = (float)A1i[e];
            float b2r = (float)A2r[e], b2i = (float)A2i[e];
            float b3r = (float)A3r[e], b3i = (float)A3i[e];
            if (m) {
                cmulw(b1r, b1i, w1r, w1i);
                cmulw(b2r, b2i, w2r, w2i);
                cmulw(b3r, b3i, w3r, w3i);
            }
            const float a0r = (float)A0r[e], a0i = (float)A0i[e];
            const float u0r = a0r + b2r, u0i = a0i + b2i;
            const float u1r = a0r - b2r, u1i = a0i - b2i;
            const float u2r = b1r + b3r, u2i = b1i + b3i;
            const float dr  = b1r - b3r, di  = b1i - b3i;
            const float u3r = -di, u3i = dr;                 // +i*(b1-b3)
            O0r[e] = (_Float16)(u0r + u2r); O0i[e] = (_Float16)(u0i + u2i);
            O1r[e] = (_Float16)(u1r + u3r); O1i[e] = (_Float16)(u1i + u3i);
            O2r[e] = (_Float16)(u0r - u2r); O2i[e] = (_Float16)(u0i - u2i);
            O3r[e] = (_Float16)(u1r - u3r); O3i[e] = (_Float16)(u1i - u3i);
        }
        *(h16x4*)&Lre[i0][c4] = O0r;  *(h16x4*)&Lim[i0][c4] = O0i;
        *(h16x4*)&Lre[i1][c4] = O1r;  *(h16x4*)&Lim[i1][c4] = O1i;
        *(h16x4*)&Lre[i2][c4] = O2r;  *(h16x4*)&Lim[i2][c4] = O2i;
        *(h16x4*)&Lre[i3][c4] = O3r;  *(h16x4*)&Lim[i3][c4] = O3i;
    }
    __syncthreads();
}

// ---- forward pass A: FFT over n1, twiddle, FUSED fft4_fwd (x1/128),
// x fp32 -> z bf16 (unchanged from passing rounds 16-23)
extern "C" __global__ void __launch_bounds__(512)
fft_fwd_a(const float* __restrict__ x, short* __restrict__ zre, short* __restrict__ zim) {
    __shared__ __align__(16) _Float16 Lre[64][136];
    __shared__ __align__(16) _Float16 Lim[64][136];
    __shared__ float wre[48], wim[48];
    __shared__ float twr[64], twi[64];
    const int tid = threadIdx.x;
    SETUP_TABLE48();
    DECODE_BCT();   // dg = n2
    if (tid >= 64 && tid < 128) {
        const int s1 = tid - 64;
        float sn, cs;
        sincosf(-(TWO_PI / 4096.0f) * (float)(dg * dr4(s1)), &sn, &cs);
        twr[s1] = cs; twi[s1] = sn;
    }
    for (int idx = tid; idx < 2048; idx += 512) {
        const int n1 = idx >> 5, q = idx & 31, blk = q >> 3, f4 = q & 7;
        const int cl = blk * 32 + f4 * 4;
        const float4 v = *(const float4*)(x + GADDR(n1 * 64 + dg, blk, f4));
        h16x4 hv, hz;
        hv[0] = (_Float16)v.x; hv[1] = (_Float16)v.y;
        hv[2] = (_Float16)v.z; hv[3] = (_Float16)v.w;
        hz[0] = (_Float16)0.f; hz[1] = (_Float16)0.f;
        hz[2] = (_Float16)0.f; hz[3] = (_Float16)0.f;
        *(h16x4*)&Lre[n1][cl] = hv;
        *(h16x4*)&Lim[n1][cl] = hz;
    }
    fft64_dif4v<136>(Lre, Lim, wre, wim, (tid & 31) * 4, tid >> 5);
    {
        const int s1 = tid >> 3, f4 = tid & 7;
        const float cs = twr[s1], sn = twi[s1];
        f32x4 r[4], m[4];
#pragma unroll
        for (int blk = 0; blk < 4; ++blk) {
            const int cl = blk * 32 + f4 * 4;
            const h16x4 hr = *(const h16x4*)&Lre[s1][cl];
            const h16x4 hi = *(const h16x4*)&Lim[s1][cl];
#pragma unroll
            for (int e = 0; e < 4; ++e) {
                const float vr = (float)hr[e], vi = (float)hi[e];
                r[blk][e] = vr * cs - vi * sn;
                m[blk][e] = vr * sn + vi * cs;
            }
        }
        const float sc = 1.0f / 128.0f;
        f32x4 yr[4], ym[4];
#pragma unroll
        for (int e = 0; e < 4; ++e) {
            const float r0 = r[0][e], r1 = r[1][e], r2 = r[2][e], r3 = r[3][e];
            const float m0 = m[0][e], m1 = m[1][e], m2 = m[2][e], m3 = m[3][e];
            yr[0][e] = (r0 + r1 + r2 + r3) * sc;  ym[0][e] = (m0 + m1 + m2 + m3) * sc;
            yr[1][e] = (r0 + m1 - r2 - m3) * sc;  ym[1][e] = (m0 - r1 - m2 + r3) * sc;
            yr[2][e] = (r0 - r1 + r2 - r3) * sc;  ym[2][e] = (m0 - m1 + m2 - m3) * sc;
            yr[3][e] = (r0 - m1 - r2 + m3) * sc;  ym[3][e] = (m0 + r1 - m2 - r3) * sc;
        }
#pragma unroll
        for (int blk = 0; blk < 4; ++blk) {
            bf16x4 pr, pi;
#pragma unroll
            for (int e = 0; e < 4; ++e) {
                pr[e] = f2bf(yr[blk][e]);
                pi[e] = f2bf(ym[blk][e]);
            }
            const size_t g = GADDR(s1 * 64 + dg, blk, f4);
            *(bf16x4*)(zre + g) = pr;
            *(bf16x4*)(zim + g) = pi;
        }
    }
}

// ---- inverse pass B: inverse twiddle (table) + FUSED ifft4 (x1/128) on
// load, inverse FFT over k1, write REAL fp32 into d_out (unchanged R20-23)
extern "C" __global__ void __launch_bounds__(512)
fft_inv_b(const short* __restrict__ zre, const short* __restrict__ zim,
          float* __restrict__ out) {
    __shared__ __align__(16) _Float16 Lre[64][136];
    __shared__ __align__(16) _Float16 Lim[64][136];
    __shared__ float wre[48], wim[48];
    __shared__ float twr[64], twi[64];
    const int tid = threadIdx.x;
    SETUP_TABLE48();
    DECODE_BCT();   // dg = n2
    if (tid >= 64 && tid < 128) {
        const int s1 = tid - 64;
        float sn, cs;
        sincosf((TWO_PI / 4096.0f) * (float)(dg * dr4(s1)), &sn, &cs);
        twr[s1] = cs; twi[s1] = sn;
    }
    __syncthreads();   // twiddle table ready before the load sweep uses it
    {
        const int s1 = tid >> 3, f4 = tid & 7;
        const float cs = twr[s1], sn = twi[s1];
        f32x4 r[4], m[4];
#pragma unroll
        for (int blk = 0; blk < 4; ++blk) {
            const size_t g = GADDR(s1 * 64 + dg, blk, f4);
            const bf16x4 vr = *(const bf16x4*)(zre + g);
            const bf16x4 vi = *(const bf16x4*)(zim + g);
#pragma unroll
            for (int e = 0; e < 4; ++e) {
                const float ar = bf2f(vr[e]), ai = bf2f(vi[e]);
                r[blk][e] = ar * cs - ai * sn;
                m[blk][e] = ar * sn + ai * cs;
            }
        }
        const float sc = 1.0f / 128.0f;
        f32x4 yr[4], ym[4];
#pragma unroll
        for (int e = 0; e < 4; ++e) {
            const float r0 = r[0][e], r1 = r[1][e], r2 = r[2][e], r3 = r[3][e];
            const float m0 = m[0][e], m1 = m[1][e], m2 = m[2][e], m3 = m[3][e];
            yr[0][e] = (r0 + r1 + r2 + r3) * sc;  ym[0][e] = (m0 + m1 + m2 + m3) * sc;
            yr[1][e] = (r0 - m1 - r2 + m3) * sc;  ym[1][e] = (m0 + r1 - m2 - r3) * sc;
            yr[2][e] = (r0 - r1 + r2 - r3) * sc;  ym[2][e] = (m0 - m1 + m2 - m3) * sc;
            yr[3][e] = (r0 + m1 - r2 - m3) * sc;  ym[3][e] = (m0 - r1 - m2 + r3) * sc;
        }
#pragma unroll
        for (int blk = 0; blk < 4; ++blk) {
            const int cl = blk * 32 + f4 * 4;
            h16x4 hr, hi;
#pragma unroll
            for (int e = 0; e < 4; ++e) {
                hr[e] = (_Float16)yr[blk][e];
                hi[e] = (_Float16)ym[blk][e];
            }
            *(h16x4*)&Lre[s1][cl] = hr;
            *(h16x4*)&Lim[s1][cl] = hi;
        }
    }
    fft64_dit4v<136>(Lre, Lim, wre, wim, (tid & 31) * 4, tid >> 5);
    for (int idx = tid; idx < 2048; idx += 512) {
        const int n1 = idx >> 5, q = idx & 31, blk = q >> 3, f4 = q & 7;
        const int cl = blk * 32 + f4 * 4;
        const h16x4 hr = *(const h16x4*)&Lre[n1][cl];
        float4 o;
        o.x = (float)hr[0]; o.y = (float)hr[1];
        o.z = (float)hr[2]; o.w = (float)hr[3];
        *(float4*)(out + GADDR(n1 * 64 + dg, blk, f4)) = o;
    }
}

// ---------------------------------------------------------------------------
// Weight prep: fold complex 2x2 into W_big bf16 [L][blk][n][k], in d_out.
// ---------------------------------------------------------------------------
extern "C" __global__ void __launch_bounds__(256)
wprep(const float* __restrict__ w1, const float* __restrict__ w2,
      short* __restrict__ wb) {
    const int i4  = blockIdx.x * 256 + threadIdx.x;
    const int k0  = (i4 & 63) * 4;
    const int n   = (i4 >> 6) & 255;
    const int blk = (i4 >> 14) & 3;
    const int L   = i4 >> 16;
    const float* w = L ? w2 : w1;
    bf16x4 pv;
#pragma unroll
    for (int j = 0; j < 4; ++j) {
        const int k = k0 + j;
        float v;
        if (k < 128) {
            v = (n < 128) ? w[blk * 16384 + k * 128 + n]
                          : w[65536 + blk * 16384 + k * 128 + (n - 128)];
        } else {
            v = (n < 128) ? -w[65536 + blk * 16384 + (k - 128) * 128 + n]
                          :  w[blk * 16384 + (k - 128) * 128 + (n - 128)];
        }
        pv[j] = f2bf(v);
    }
    *(bf16x4*)(wb + (size_t)i4 * 4) = pv;
}

// ---------------------------------------------------------------------------
// FUSED MFMA MLP layer + n2-FFT, in place. OPERAND-SWAPPED MFMA:
// acc = mfma(Bf, af) computes (A*W)^T, so each lane holds 4 CONSECUTIVE n
// for one token row -> vectorized bf16x4 epilogues (LDS + global).
// ---------------------------------------------------------------------------
#define MITER 4

__device__ __forceinline__ void stage_tile(const short* __restrict__ zre,
                                           const short* __restrict__ zim,
                                           char* Abuf, int rowbase, int blk,
                                           int wave, int lane) {
#pragma unroll
    for (int it = 0; it < 4; ++it) {
        const int chunk = wave * 256 + it * 64 + lane;   // 16B chunk id, 0..2047
        const int row   = chunk >> 5;
        const unsigned kbyte = ((unsigned)((chunk & 31) << 4)) ^ ((unsigned)((row & 7) << 4));
        const int k0 = (int)(kbyte >> 1);                // element k, multiple of 8
        const short* src = (k0 < 128) ? zre : zim;
        const size_t g = (size_t)(rowbase + row) * 512 + blk * 128 + (k0 & 127);
        unsigned* lp = (unsigned*)(Abuf + (wave * 4096 + it * 1024));  // wave-uniform
        __builtin_amdgcn_global_load_lds((const unsigned*)(src + g), lp, 16, 0, 0);
    }
}

template<int LAYER>
__global__ void __launch_bounds__(512)
mlp_fused(short* __restrict__ zre, short* __restrict__ zim,
          const short* __restrict__ wb, const float* __restrict__ bias) {
    __shared__ __align__(16) char As[2][64 * 256 * 2];   // 2 x 32 KB bf16, swizzled
    __shared__ float wre[48], wim[48];

    const int blk  = blockIdx.y;
    const int tid  = threadIdx.x;
    const int wave = tid >> 6;
    const int lane = tid & 63;
    const int lrow = lane & 15;
    const int lk   = lane >> 4;
    const int cg   = tid & 31;     // FFT: 4-channel group
    const int fh   = tid >> 5;     // FFT: butterfly index 0..15
    SETUP_TABLE48();

    bf16x8 Bf[2][8];
#pragma unroll
    for (int nt = 0; nt < 2; ++nt) {
        const int n = wave * 32 + nt * 16 + lrow;
#pragma unroll
        for (int ks = 0; ks < 8; ++ks) {
            Bf[nt][ks] = *(const bf16x8*)(wb + ((size_t)(blk * 256 + n) * 256 + ks * 32 + lk * 8));
        }
    }

    // bias for the 4 consecutive n this lane owns per fragment (swapped layout)
    f32x4 bv4[2];
#pragma unroll
    for (int nt = 0; nt < 2; ++nt) {
        const int n0 = wave * 32 + nt * 16 + lk * 4;
        const float* bp = bias + ((n0 < 128) ? (blk * 128 + n0)
                                             : (512 + blk * 128 + (n0 - 128)));
        bv4[nt] = *(const f32x4*)bp;
    }

    stage_tile(zre, zim, As[0], blockIdx.x * MITER * 64, blk, wave, lane);

    for (int t = 0; t < MITER; ++t) {
        __syncthreads();   // staged tile t visible

        char* Ab = As[t & 1];
        const int rowbase = (blockIdx.x * MITER + t) * 64;

        if (LAYER == 1) {
            // ---- forward n2-FFT on the staged tile (cols = channels)
            dif_stage_A(Ab, wre, wim, cg, fh, 0);
            __syncthreads();
            dif_stage_A(Ab, wre, wim, cg, fh, 1);
            __syncthreads();
            dif_stage_A(Ab, wre, wim, cg, fh, 2);
            __syncthreads();
        }

        if (t + 1 < MITER)
            stage_tile(zre, zim, As[(t + 1) & 1],
                       (blockIdx.x * MITER + t + 1) * 64, blk, wave, lane);

        f32x4 acc[4][2];
#pragma unroll
        for (int mt = 0; mt < 4; ++mt)
#pragma unroll
            for (int nt = 0; nt < 2; ++nt)
                acc[mt][nt] = (f32x4){0.f, 0.f, 0.f, 0.f};

#pragma unroll
        for (int ks = 0; ks < 8; ++ks) {
            bf16x8 af[4];
#pragma unroll
            for (int mt = 0; mt < 4; ++mt) {
                const int row = mt * 16 + lrow;
                const int k0  = ks * 32 + lk * 8;
                const unsigned byteoff =
                    ((unsigned)(row * 512 + k0 * 2)) ^ ((unsigned)((row & 7) << 4));
                af[mt] = *(const bf16x8*)(Ab + byteoff);
            }
            // operand-swapped: D = Bf(A-op) x af(B-op) = (A*W)^T
#pragma unroll
            for (int mt = 0; mt < 4; ++mt)
#pragma unroll
                for (int nt = 0; nt < 2; ++nt)
                    acc[mt][nt] = __builtin_amdgcn_mfma_f32_16x16x32_bf16(
                        Bf[nt][ks], af[mt], acc[mt][nt], 0, 0, 0);
        }

        if (LAYER == 1) {
            // ---- relu + bias, vectorized store (lane: row = mt*16+lrow,
            //      n = wave*32 + nt*16 + lk*4 + r)
#pragma unroll
            for (int nt = 0; nt < 2; ++nt) {
                const int n0 = wave * 32 + nt * 16 + lk * 4;
                short* dst = (n0 < 128) ? zre : zim;
                const int colb = blk * 128 + (n0 & 127);
#pragma unroll
                for (int mt = 0; mt < 4; ++mt) {
                    const int row = rowbase + mt * 16 + lrow;
                    bf16x4 pv;
#pragma unroll
                    for (int r = 0; r < 4; ++r)
                        pv[r] = f2bf(fmaxf(acc[mt][nt][r] + bv4[nt][r], 0.0f));
                    *(bf16x4*)(dst + (size_t)row * 512 + colb) = pv;
                }
            }
        } else {
            // ---- softshrink + bias, vectorized write into LDS tile
            __syncthreads();   // all MFMA reads of Ab complete
#pragma unroll
            for (int nt = 0; nt < 2; ++nt) {
                const int n0 = wave * 32 + nt * 16 + lk * 4;
                const int cb = n0 * 2;     // byte col: re 0..255, im 256..511
#pragma unroll
                for (int mt = 0; mt < 4; ++mt) {
                    const int row = mt * 16 + lrow;
                    bf16x4 pv;
#pragma unroll
                    for (int r = 0; r < 4; ++r) {
                        float v = acc[mt][nt][r] + bv4[nt][r];
                        v = (v > 0.01f) ? v - 0.01f : ((v < -0.01f) ? v + 0.01f : 0.0f);
                        pv[r] = f2bf(v);
                    }
                    *(bf16x4*)(Ab + row * 512 + (cb ^ ((row & 7) << 4))) = pv;
                }
            }
            __syncthreads();
            dit_stage_A(Ab, wre, wim, cg, fh, 2);
            __syncthreads();
            dit_stage_A(Ab, wre, wim, cg, fh, 1);
            __syncthreads();
            dit_stage_A(Ab, wre, wim, cg, fh, 0);
            __syncthreads();
            // ---- PLAIN de-swizzle store (rows natural n2; twiddle in inv_b)
#pragma unroll
            for (int kk = 0; kk < 4; ++kk) {
                const int idx = tid + kk * 512;    // 2048 = 64 rows x 2 planes x 16 chunks
                const int row = idx >> 5;
                const int q = idx & 31;
                const int p = q >> 4;              // 0 = re, 1 = im
                const int c = q & 15;              // 8-ch chunk within 128-ch window
                const int cbyte = p * 256 + c * 16;
                const bf16x8 v = *(const bf16x8*)(Ab + row * 512 + (cbyte ^ ((row & 7) << 4)));
                short* dst = p ? zim : zre;
                *(bf16x8*)(dst + (size_t)(rowbase + row) * 512 + blk * 128 + c * 8) = v;
            }
        }
    }
}

extern "C" void kernel_launch(void* const* d_in, const int* in_sizes, int n_in,
                              void* d_out, int out_size, void* d_ws, size_t ws_size,
                              hipStream_t stream) {
    const float* x  = (const float*)d_in[0];
    const float* w1 = (const float*)d_in[1];
    const float* w2 = (const float*)d_in[2];
    const float* b1 = (const float*)d_in[3];
    const float* b2 = (const float*)d_in[4];

    float* out = (float*)d_out;
    short* zre = (short*)d_ws;            // bf16 real plane, 32 MiB
    short* zim = zre + 16777216;          // bf16 imag plane, 32 MiB
    short* wb  = (short*)d_out;           // 1 MiB W_big scratch inside d_out
    const size_t WB_L = 4ull * 256 * 256;

    wprep<<<512, 256, 0, stream>>>(w1, w2, wb);

    // forward: pass A (n1-FFT + twiddle + fft4); n2-FFT fused into MLP layer 1
    fft_fwd_a<<<2048, 512, 0, stream>>>(x, zre, zim);

    mlp_fused<1><<<dim3(32768 / (64 * MITER), 4), 512, 0, stream>>>(zre, zim, wb, b1);
    mlp_fused<2><<<dim3(32768 / (64 * MITER), 4), 512, 0, stream>>>(zre, zim, wb + WB_L, b2);

    // inverse: inverse n2-FFT fused into MLP layer 2; inv_b applies the
    // inverse twiddle + ifft4 on load, then finishes over k1
    fft_inv_b<<<2048, 512, 0, stream>>>(zre, zim, out);
}